// Round 3
// baseline (269.365 us; speedup 1.0000x reference)
//
#include <hip/hip_runtime.h>
#include <stdint.h>

#define N_Q 16384
#define M_P 1024
#define D_K 1024

typedef __attribute__((ext_vector_type(8))) __bf16 bf16x8;
typedef __attribute__((ext_vector_type(4))) float floatx4;

#define AS1 __attribute__((address_space(1)))
#define AS3 __attribute__((address_space(3)))

__device__ __forceinline__ unsigned short f2bf(float f) {
    unsigned int u = __float_as_uint(f);
    u += 0x7fffu + ((u >> 16) & 1u);   // round-to-nearest-even
    return (unsigned short)(u >> 16);
}
__device__ __forceinline__ float bf2f(unsigned short h) {
    return __uint_as_float(((unsigned int)h) << 16);
}

// ---------------------------------------------------------------------------
// Fused convert: blocks [0, 16384) split query fp32 -> bf16 hi/lo;
// blocks [16384, 17408) split proto row + compute p2[m].
// ---------------------------------------------------------------------------
__global__ __launch_bounds__(256) void convert_all_kernel(
    const float* __restrict__ query, unsigned short* __restrict__ qh,
    unsigned short* __restrict__ ql, const float* __restrict__ proto,
    unsigned short* __restrict__ ph, unsigned short* __restrict__ pl,
    float* __restrict__ p2) {
    __shared__ float sred[4];
    int b = blockIdx.x;
    int t = threadIdx.x;
    if (b < N_Q) {
        // query part: 16384 blocks x 256 threads x 1 float4 == 16M floats
        int idx = b * 256 + t;
        floatx4 v = __builtin_nontemporal_load((const floatx4*)query + idx);
        ushort4 h, l;
        h.x = f2bf(v.x); l.x = f2bf(v.x - bf2f(h.x));
        h.y = f2bf(v.y); l.y = f2bf(v.y - bf2f(h.y));
        h.z = f2bf(v.z); l.z = f2bf(v.z - bf2f(h.z));
        h.w = f2bf(v.w); l.w = f2bf(v.w - bf2f(h.w));
        ((ushort4*)qh)[idx] = h;
        ((ushort4*)ql)[idx] = l;
    } else {
        // proto part: one block per proto row, also reduce ||p||^2
        int m = b - N_Q;
        size_t base4 = (size_t)m * (D_K / 4) + t;
        float4 v = ((const float4*)proto)[base4];
        ushort4 h, l;
        h.x = f2bf(v.x); l.x = f2bf(v.x - bf2f(h.x));
        h.y = f2bf(v.y); l.y = f2bf(v.y - bf2f(h.y));
        h.z = f2bf(v.z); l.z = f2bf(v.z - bf2f(h.z));
        h.w = f2bf(v.w); l.w = f2bf(v.w - bf2f(h.w));
        ((ushort4*)ph)[base4] = h;
        ((ushort4*)pl)[base4] = l;
        float sq = v.x * v.x + v.y * v.y + v.z * v.z + v.w * v.w;
#pragma unroll
        for (int off = 1; off < 64; off <<= 1) sq += __shfl_xor(sq, off);
        if ((t & 63) == 0) sred[t >> 6] = sq;
        __syncthreads();
        if (t == 0) p2[m] = sred[0] + sred[1] + sred[2] + sred[3];
    }
}

// ---------------------------------------------------------------------------
// GEMM: logits[n,m] = 2 * sum_d q[n,d]*p[m,d] - p2[m], via bf16 hi/lo split:
//   qp = qh.ph + qh.pl + ql.ph   (ql.pl dropped, ~1e-4 error)
// 128x128 tile, BK=32, 4 waves -> 2x2 of 64x64, mfma_f32_16x16x32_bf16.
//
// LDS layout is FRAGMENT-ORDER: staging lane l loads global
// (row = l&15, kchunk = l>>4), so within each 16-row subtile the data for
// (row r, kchunk c) sits at (c*16 + r)*16B. Compute-side fragment reads are
// then lds_base + lane*16B: a contiguous 1024B wave access -> zero bank
// conflicts (R1 fix: row-major layout cost ~4 extra bank-cycles/ds_read,
// SQ_LDS_BANK_CONFLICT=8.4M).
// ---------------------------------------------------------------------------
__global__ __launch_bounds__(256, 3) void gemm_logits_kernel(
    const unsigned short* __restrict__ qh, const unsigned short* __restrict__ ql,
    const unsigned short* __restrict__ ph, const unsigned short* __restrict__ pl,
    const float* __restrict__ p2, float* __restrict__ out) {
    __shared__ unsigned short lds[4 * 128 * 32];  // Ah | Al | Bh | Bl, 32 KB

    const int tid = threadIdx.x;
    const int wave = tid >> 6;
    const int lane = tid & 63;
    const int nt = blockIdx.x & 127;   // query tile (consecutive blocks share mt)
    const int mt = blockIdx.x >> 7;    // proto tile
    const int row0 = nt * 128;
    const int col0 = mt * 128;

    unsigned short* sAh = lds;
    unsigned short* sAl = lds + 4096;
    unsigned short* sBh = lds + 8192;
    unsigned short* sBl = lds + 12288;

    // Staging assignment: one wave per tile.
    const unsigned short* gsrc;
    unsigned short* ldst;
    int grow0;
    if (wave == 0)      { gsrc = qh; grow0 = row0; ldst = sAh; }
    else if (wave == 1) { gsrc = ql; grow0 = row0; ldst = sAl; }
    else if (wave == 2) { gsrc = ph; grow0 = col0; ldst = sBh; }
    else                { gsrc = pl; grow0 = col0; ldst = sBl; }

    // Fragment-order staging: lane l -> (row = l&15, kchunk = l>>4).
    // HW lands lane l's 16B at ldst + iter*512 + l*8 shorts.
    const int rl = lane & 15;
    const int cio = lane >> 4;
    const unsigned short* gbase = gsrc + (size_t)(grow0 + rl) * D_K + cio * 8;

    floatx4 zero = {0.0f, 0.0f, 0.0f, 0.0f};
    floatx4 acc[4][4];
#pragma unroll
    for (int i = 0; i < 4; ++i)
#pragma unroll
        for (int j = 0; j < 4; ++j) acc[i][j] = zero;

    const int wrow = (wave & 1) * 64;
    const int wcol = (wave >> 1) * 64;
    const int rsel = lane & 15;
    const int kq = lane >> 4;
    const int sA0 = (wrow >> 4);  // first A subtile index for this wave
    const int sB0 = (wcol >> 4);

    for (int kt = 0; kt < D_K / 32; ++kt) {
        // ---- stage global -> LDS (async, 16B/lane) ----
#pragma unroll
        for (int i = 0; i < 8; ++i) {
            const unsigned short* gp = gbase + (size_t)i * 16 * D_K + kt * 32;
            __builtin_amdgcn_global_load_lds(
                (const AS1 unsigned int*)(const void*)gp,
                (AS3 unsigned int*)(void*)(ldst + i * 512), 16, 0, 0);
        }
        __syncthreads();

        // ---- fragment loads: base + lane*16B, conflict-free ----
        bf16x8 ah[4], al[4], bh[4], bl[4];
#pragma unroll
        for (int i = 0; i < 4; ++i) {
            const int aoff = (sA0 + i) * 512 + lane * 8;
            ah[i] = *(const bf16x8*)(sAh + aoff);
            al[i] = *(const bf16x8*)(sAl + aoff);
            const int boff = (sB0 + i) * 512 + lane * 8;
            bh[i] = *(const bf16x8*)(sBh + boff);
            bl[i] = *(const bf16x8*)(sBl + boff);
        }

        // ---- 3-term MFMA accumulate ----
#pragma unroll
        for (int i = 0; i < 4; ++i)
#pragma unroll
            for (int j = 0; j < 4; ++j) {
                acc[i][j] = __builtin_amdgcn_mfma_f32_16x16x32_bf16(ah[i], bh[j], acc[i][j], 0, 0, 0);
                acc[i][j] = __builtin_amdgcn_mfma_f32_16x16x32_bf16(ah[i], bl[j], acc[i][j], 0, 0, 0);
                acc[i][j] = __builtin_amdgcn_mfma_f32_16x16x32_bf16(al[i], bh[j], acc[i][j], 0, 0, 0);
            }
        __syncthreads();
    }

    // ---- epilogue: logits = 2*qp - p2[col] ----
    // C layout (verified m89/m91): col = lane&15, row = (lane>>4)*4 + reg
#pragma unroll
    for (int j = 0; j < 4; ++j) {
        const int gc = col0 + wcol + j * 16 + rsel;
        const float p2v = p2[gc];
#pragma unroll
        for (int i = 0; i < 4; ++i) {
            const int gr = row0 + wrow + i * 16 + kq * 4;
#pragma unroll
            for (int r = 0; r < 4; ++r) {
                out[(size_t)(gr + r) * M_P + gc] = 2.0f * acc[i][j][r] - p2v;
            }
        }
    }
}

// ---------------------------------------------------------------------------
// Fallback (tiny workspace): naive fp32 logits, p2 folded in per-thread.
// ---------------------------------------------------------------------------
__global__ __launch_bounds__(256) void naive_logits_kernel(
    const float* __restrict__ query, const float* __restrict__ proto,
    float* __restrict__ out) {
    __shared__ float qs[D_K];
    int n = blockIdx.x;
    int t = threadIdx.x;
    ((float4*)qs)[t] = ((const float4*)(query + (size_t)n * D_K))[t];
    __syncthreads();
    float acc[4] = {0.f, 0.f, 0.f, 0.f};
    float pp[4] = {0.f, 0.f, 0.f, 0.f};
    for (int d = 0; d < D_K; d += 4) {
        float4 qv = *(const float4*)(qs + d);
#pragma unroll
        for (int j = 0; j < 4; ++j) {
            const float4 pv = *(const float4*)(proto + (size_t)(t + 256 * j) * D_K + d);
            acc[j] += qv.x * pv.x + qv.y * pv.y + qv.z * pv.z + qv.w * pv.w;
            pp[j] += pv.x * pv.x + pv.y * pv.y + pv.z * pv.z + pv.w * pv.w;
        }
    }
#pragma unroll
    for (int j = 0; j < 4; ++j)
        out[(size_t)n * M_P + t + 256 * j] = 2.0f * acc[j] - pp[j];
}

// ---------------------------------------------------------------------------
// In-place row softmax over M=1024 (one block/row, one float4/thread).
// ---------------------------------------------------------------------------
__global__ __launch_bounds__(256) void softmax_kernel(float* __restrict__ out) {
    int n = blockIdx.x;
    int t = threadIdx.x;
    floatx4* row = (floatx4*)(out + (size_t)n * M_P);
    floatx4 v = row[t];
    float mx = fmaxf(fmaxf(v.x, v.y), fmaxf(v.z, v.w));
#pragma unroll
    for (int off = 1; off < 64; off <<= 1) mx = fmaxf(mx, __shfl_xor(mx, off));
    __shared__ float smax[4];
    __shared__ float ssum[4];
    int wave = t >> 6, lane = t & 63;
    if (lane == 0) smax[wave] = mx;
    __syncthreads();
    mx = fmaxf(fmaxf(smax[0], smax[1]), fmaxf(smax[2], smax[3]));
    float e0 = __expf(v.x - mx), e1 = __expf(v.y - mx);
    float e2 = __expf(v.z - mx), e3 = __expf(v.w - mx);
    float s = e0 + e1 + e2 + e3;
#pragma unroll
    for (int off = 1; off < 64; off <<= 1) s += __shfl_xor(s, off);
    if (lane == 0) ssum[wave] = s;
    __syncthreads();
    float inv = 1.0f / (ssum[0] + ssum[1] + ssum[2] + ssum[3]);
    floatx4 o;
    o.x = e0 * inv; o.y = e1 * inv; o.z = e2 * inv; o.w = e3 * inv;
    __builtin_nontemporal_store(o, row + t);
}

extern "C" void kernel_launch(void* const* d_in, const int* in_sizes, int n_in,
                              void* d_out, int out_size, void* d_ws, size_t ws_size,
                              hipStream_t stream) {
    const float* query = (const float*)d_in[0];
    const float* proto = (const float*)d_in[1];
    float* out = (float*)d_out;

    const size_t qElems = (size_t)N_Q * D_K;   // 16M
    const size_t pElems = (size_t)M_P * D_K;   // 1M
    const size_t needed = qElems * 2 * 2 + pElems * 2 * 2 + M_P * 4;  // ~68 MiB

    if (ws_size >= needed) {
        unsigned short* qh = (unsigned short*)d_ws;
        unsigned short* ql = qh + qElems;
        unsigned short* ph = ql + qElems;
        unsigned short* pl = ph + pElems;
        float* p2 = (float*)(pl + pElems);

        convert_all_kernel<<<N_Q + M_P, 256, 0, stream>>>(
            query, qh, ql, proto, ph, pl, p2);
        gemm_logits_kernel<<<(N_Q / 128) * (M_P / 128), 256, 0, stream>>>(
            qh, ql, ph, pl, p2, out);
    } else {
        naive_logits_kernel<<<N_Q, 256, 0, stream>>>(query, proto, out);
    }
    softmax_kernel<<<N_Q, 256, 0, stream>>>(out);
}

// Round 4
// 235.020 us; speedup vs baseline: 1.1461x; 1.1461x over previous
//
#include <hip/hip_runtime.h>
#include <stdint.h>

#define N_Q 16384
#define M_P 1024
#define D_K 1024

typedef __attribute__((ext_vector_type(8))) __bf16 bf16x8;
typedef __attribute__((ext_vector_type(4))) float floatx4;
typedef __attribute__((ext_vector_type(8))) unsigned short ushort8v;

#define AS1 __attribute__((address_space(1)))
#define AS3 __attribute__((address_space(3)))

__device__ __forceinline__ unsigned short f2bf(float f) {
    unsigned int u = __float_as_uint(f);
    u += 0x7fffu + ((u >> 16) & 1u);   // round-to-nearest-even
    return (unsigned short)(u >> 16);
}
__device__ __forceinline__ float bf2f(unsigned short h) {
    return __uint_as_float(((unsigned int)h) << 16);
}

// ---------------------------------------------------------------------------
// Fused convert: blocks [0, 8192) split query fp32 -> bf16 hi/lo (8 floats
// per thread, 16B ushort8 stores); blocks [8192, 9216) split proto row and
// compute p2[m].
// ---------------------------------------------------------------------------
__global__ __launch_bounds__(256) void convert_all_kernel(
    const float* __restrict__ query, unsigned short* __restrict__ qh,
    unsigned short* __restrict__ ql, const float* __restrict__ proto,
    unsigned short* __restrict__ ph, unsigned short* __restrict__ pl,
    float* __restrict__ p2) {
    __shared__ float sred[4];
    int b = blockIdx.x;
    int t = threadIdx.x;
    if (b < 8192) {
        size_t idx = (size_t)b * 256 + t;            // float8 index
        const floatx4* src = (const floatx4*)query + idx * 2;
        floatx4 v0 = __builtin_nontemporal_load(src);
        floatx4 v1 = __builtin_nontemporal_load(src + 1);
        ushort8v h, l;
        h[0] = f2bf(v0.x); l[0] = f2bf(v0.x - bf2f(h[0]));
        h[1] = f2bf(v0.y); l[1] = f2bf(v0.y - bf2f(h[1]));
        h[2] = f2bf(v0.z); l[2] = f2bf(v0.z - bf2f(h[2]));
        h[3] = f2bf(v0.w); l[3] = f2bf(v0.w - bf2f(h[3]));
        h[4] = f2bf(v1.x); l[4] = f2bf(v1.x - bf2f(h[4]));
        h[5] = f2bf(v1.y); l[5] = f2bf(v1.y - bf2f(h[5]));
        h[6] = f2bf(v1.z); l[6] = f2bf(v1.z - bf2f(h[6]));
        h[7] = f2bf(v1.w); l[7] = f2bf(v1.w - bf2f(h[7]));
        ((ushort8v*)qh)[idx] = h;
        ((ushort8v*)ql)[idx] = l;
    } else {
        // proto part: one block per proto row, also reduce ||p||^2
        int m = b - 8192;
        size_t base4 = (size_t)m * (D_K / 4) + t;
        float4 v = ((const float4*)proto)[base4];
        ushort4 h, l;
        h.x = f2bf(v.x); l.x = f2bf(v.x - bf2f(h.x));
        h.y = f2bf(v.y); l.y = f2bf(v.y - bf2f(h.y));
        h.z = f2bf(v.z); l.z = f2bf(v.z - bf2f(h.z));
        h.w = f2bf(v.w); l.w = f2bf(v.w - bf2f(h.w));
        ((ushort4*)ph)[base4] = h;
        ((ushort4*)pl)[base4] = l;
        float sq = v.x * v.x + v.y * v.y + v.z * v.z + v.w * v.w;
#pragma unroll
        for (int off = 1; off < 64; off <<= 1) sq += __shfl_xor(sq, off);
        if ((t & 63) == 0) sred[t >> 6] = sq;
        __syncthreads();
        if (t == 0) p2[m] = sred[0] + sred[1] + sred[2] + sred[3];
    }
}

// ---------------------------------------------------------------------------
// GEMM: logits[n,m] = 2 * sum_d q[n,d]*p[m,d] - p2[m], via bf16 hi/lo split:
//   qp = qh.ph + qh.pl + ql.ph   (ql.pl dropped, ~1e-4 error)
// 128x128 tile, BK=32, 4 waves -> 2x2 of 64x64, mfma_f32_16x16x32_bf16.
//
// Staging (R3 post-mortem): global side MUST stay quad-coalesced (lane quad
// = one row's contiguous 64B; R3's fragment-order staging scattered lanes
// across rows -> 4x VMEM transactions -> 106->147us). LDS bank conflicts are
// instead broken with an XOR swizzle that keeps each quad inside its row's
// 64B: staging lane s fetches (row = s>>2, chunk = (s&3) ^ ((s>>3)&3)).
// Granule g then holds (r = g>>2, c = (g&3) ^ ((g>>3)&3)); compute lane l
// reads granule 4*(l&15) + ((l>>4) ^ (((l&15)>>1)&3)) whose bank-group g%8
// cycles all 8 groups per 8 rows -> 2 lanes/group per quarter-wave, and
// 2-way is free (m136).
// ---------------------------------------------------------------------------
__global__ __launch_bounds__(256, 3) void gemm_logits_kernel(
    const unsigned short* __restrict__ qh, const unsigned short* __restrict__ ql,
    const unsigned short* __restrict__ ph, const unsigned short* __restrict__ pl,
    const float* __restrict__ p2, float* __restrict__ out) {
    __shared__ unsigned short lds[4 * 128 * 32];  // Ah | Al | Bh | Bl, 32 KB

    const int tid = threadIdx.x;
    const int wave = tid >> 6;
    const int lane = tid & 63;
    const int nt = blockIdx.x & 127;   // query tile (consecutive blocks share mt)
    const int mt = blockIdx.x >> 7;    // proto tile
    const int row0 = nt * 128;
    const int col0 = mt * 128;

    unsigned short* sAh = lds;
    unsigned short* sAl = lds + 4096;
    unsigned short* sBh = lds + 8192;
    unsigned short* sBl = lds + 12288;

    // Staging assignment: one wave per tile.
    const unsigned short* gsrc;
    unsigned short* ldst;
    int grow0;
    if (wave == 0)      { gsrc = qh; grow0 = row0; ldst = sAh; }
    else if (wave == 1) { gsrc = ql; grow0 = row0; ldst = sAl; }
    else if (wave == 2) { gsrc = ph; grow0 = col0; ldst = sBh; }
    else                { gsrc = pl; grow0 = col0; ldst = sBl; }

    // Quad-coalesced + XOR-swizzled staging source.
    const int rl = lane >> 2;
    const int cio = (lane & 3) ^ ((lane >> 3) & 3);
    const unsigned short* gbase = gsrc + (size_t)(grow0 + rl) * D_K + cio * 8;

    floatx4 zero = {0.0f, 0.0f, 0.0f, 0.0f};
    floatx4 acc[4][4];
#pragma unroll
    for (int i = 0; i < 4; ++i)
#pragma unroll
        for (int j = 0; j < 4; ++j) acc[i][j] = zero;

    const int wrow = (wave & 1) * 64;
    const int wcol = (wave >> 1) * 64;
    const int rsel = lane & 15;
    const int kq = lane >> 4;
    const int sA0 = (wrow >> 4);  // first A subtile index for this wave
    const int sB0 = (wcol >> 4);
    // Swizzled granule for this lane's fragment (within a 64-granule subtile)
    const int gsw = 4 * rsel + (kq ^ ((rsel >> 1) & 3));
    const int fragoff = gsw * 8;  // shorts

    for (int kt = 0; kt < D_K / 32; ++kt) {
        // ---- stage global -> LDS (async, 16B/lane) ----
#pragma unroll
        for (int i = 0; i < 8; ++i) {
            const unsigned short* gp = gbase + (size_t)i * 16 * D_K + kt * 32;
            __builtin_amdgcn_global_load_lds(
                (const AS1 unsigned int*)(const void*)gp,
                (AS3 unsigned int*)(void*)(ldst + i * 512), 16, 0, 0);
        }
        __syncthreads();

        // ---- fragment loads (swizzle-matched, ~conflict-free) ----
        bf16x8 ah[4], al[4], bh[4], bl[4];
#pragma unroll
        for (int i = 0; i < 4; ++i) {
            const int aoff = (sA0 + i) * 512 + fragoff;
            ah[i] = *(const bf16x8*)(sAh + aoff);
            al[i] = *(const bf16x8*)(sAl + aoff);
            const int boff = (sB0 + i) * 512 + fragoff;
            bh[i] = *(const bf16x8*)(sBh + boff);
            bl[i] = *(const bf16x8*)(sBl + boff);
        }

        // ---- 3-term MFMA accumulate ----
#pragma unroll
        for (int i = 0; i < 4; ++i)
#pragma unroll
            for (int j = 0; j < 4; ++j) {
                acc[i][j] = __builtin_amdgcn_mfma_f32_16x16x32_bf16(ah[i], bh[j], acc[i][j], 0, 0, 0);
                acc[i][j] = __builtin_amdgcn_mfma_f32_16x16x32_bf16(ah[i], bl[j], acc[i][j], 0, 0, 0);
                acc[i][j] = __builtin_amdgcn_mfma_f32_16x16x32_bf16(al[i], bh[j], acc[i][j], 0, 0, 0);
            }
        __syncthreads();
    }

    // ---- epilogue: logits = 2*qp - p2[col] ----
    // C layout (verified m89/m91): col = lane&15, row = (lane>>4)*4 + reg
#pragma unroll
    for (int j = 0; j < 4; ++j) {
        const int gc = col0 + wcol + j * 16 + rsel;
        const float p2v = p2[gc];
#pragma unroll
        for (int i = 0; i < 4; ++i) {
            const int gr = row0 + wrow + i * 16 + kq * 4;
#pragma unroll
            for (int r = 0; r < 4; ++r) {
                out[(size_t)(gr + r) * M_P + gc] = 2.0f * acc[i][j][r] - p2v;
            }
        }
    }
}

// ---------------------------------------------------------------------------
// Fallback (tiny workspace): naive fp32 logits, p2 folded in per-thread.
// ---------------------------------------------------------------------------
__global__ __launch_bounds__(256) void naive_logits_kernel(
    const float* __restrict__ query, const float* __restrict__ proto,
    float* __restrict__ out) {
    __shared__ float qs[D_K];
    int n = blockIdx.x;
    int t = threadIdx.x;
    ((float4*)qs)[t] = ((const float4*)(query + (size_t)n * D_K))[t];
    __syncthreads();
    float acc[4] = {0.f, 0.f, 0.f, 0.f};
    float pp[4] = {0.f, 0.f, 0.f, 0.f};
    for (int d = 0; d < D_K; d += 4) {
        float4 qv = *(const float4*)(qs + d);
#pragma unroll
        for (int j = 0; j < 4; ++j) {
            const float4 pv = *(const float4*)(proto + (size_t)(t + 256 * j) * D_K + d);
            acc[j] += qv.x * pv.x + qv.y * pv.y + qv.z * pv.z + qv.w * pv.w;
            pp[j] += pv.x * pv.x + pv.y * pv.y + pv.z * pv.z + pv.w * pv.w;
        }
    }
#pragma unroll
    for (int j = 0; j < 4; ++j)
        out[(size_t)n * M_P + t + 256 * j] = 2.0f * acc[j] - pp[j];
}

// ---------------------------------------------------------------------------
// In-place row softmax over M=1024 (one block/row, one float4/thread).
// ---------------------------------------------------------------------------
__global__ __launch_bounds__(256) void softmax_kernel(float* __restrict__ out) {
    int n = blockIdx.x;
    int t = threadIdx.x;
    floatx4* row = (floatx4*)(out + (size_t)n * M_P);
    floatx4 v = row[t];
    float mx = fmaxf(fmaxf(v.x, v.y), fmaxf(v.z, v.w));
#pragma unroll
    for (int off = 1; off < 64; off <<= 1) mx = fmaxf(mx, __shfl_xor(mx, off));
    __shared__ float smax[4];
    __shared__ float ssum[4];
    int wave = t >> 6, lane = t & 63;
    if (lane == 0) smax[wave] = mx;
    __syncthreads();
    mx = fmaxf(fmaxf(smax[0], smax[1]), fmaxf(smax[2], smax[3]));
    float e0 = __expf(v.x - mx), e1 = __expf(v.y - mx);
    float e2 = __expf(v.z - mx), e3 = __expf(v.w - mx);
    float s = e0 + e1 + e2 + e3;
#pragma unroll
    for (int off = 1; off < 64; off <<= 1) s += __shfl_xor(s, off);
    if (lane == 0) ssum[wave] = s;
    __syncthreads();
    float inv = 1.0f / (ssum[0] + ssum[1] + ssum[2] + ssum[3]);
    floatx4 o;
    o.x = e0 * inv; o.y = e1 * inv; o.z = e2 * inv; o.w = e3 * inv;
    __builtin_nontemporal_store(o, row + t);
}

extern "C" void kernel_launch(void* const* d_in, const int* in_sizes, int n_in,
                              void* d_out, int out_size, void* d_ws, size_t ws_size,
                              hipStream_t stream) {
    const float* query = (const float*)d_in[0];
    const float* proto = (const float*)d_in[1];
    float* out = (float*)d_out;

    const size_t qElems = (size_t)N_Q * D_K;   // 16M
    const size_t pElems = (size_t)M_P * D_K;   // 1M
    const size_t needed = qElems * 2 * 2 + pElems * 2 * 2 + M_P * 4;  // ~68 MiB

    if (ws_size >= needed) {
        unsigned short* qh = (unsigned short*)d_ws;
        unsigned short* ql = qh + qElems;
        unsigned short* ph = ql + qElems;
        unsigned short* pl = ph + pElems;
        float* p2 = (float*)(pl + pElems);

        convert_all_kernel<<<8192 + M_P, 256, 0, stream>>>(
            query, qh, ql, proto, ph, pl, p2);
        gemm_logits_kernel<<<(N_Q / 128) * (M_P / 128), 256, 0, stream>>>(
            qh, ql, ph, pl, p2, out);
    } else {
        naive_logits_kernel<<<N_Q, 256, 0, stream>>>(query, proto, out);
    }
    softmax_kernel<<<N_Q, 256, 0, stream>>>(out);
}

// Round 5
// 231.815 us; speedup vs baseline: 1.1620x; 1.0138x over previous
//
#include <hip/hip_runtime.h>
#include <stdint.h>

#define N_Q 16384
#define M_P 1024
#define D_K 1024

typedef __attribute__((ext_vector_type(8))) __bf16 bf16x8;
typedef __attribute__((ext_vector_type(4))) float floatx4;
typedef __attribute__((ext_vector_type(8))) unsigned short ushort8v;

#define AS1 __attribute__((address_space(1)))
#define AS3 __attribute__((address_space(3)))

__device__ __forceinline__ unsigned short f2bf(float f) {
    unsigned int u = __float_as_uint(f);
    u += 0x7fffu + ((u >> 16) & 1u);   // round-to-nearest-even
    return (unsigned short)(u >> 16);
}
__device__ __forceinline__ float bf2f(unsigned short h) {
    return __uint_as_float(((unsigned int)h) << 16);
}

// ---------------------------------------------------------------------------
// Fused convert. Blocks [0,2048): query fp32 -> bf16 hi/lo, 4 float8s per
// thread (8 independent 16B loads in flight -> latency-hiding ILP; R4 had
// 1 float8/thread over 8192 tiny blocks and ran far off BW-bound).
// Blocks [2048,3072): proto rows + p2[m].
// ---------------------------------------------------------------------------
__global__ __launch_bounds__(256) void convert_all_kernel(
    const float* __restrict__ query, unsigned short* __restrict__ qh,
    unsigned short* __restrict__ ql, const float* __restrict__ proto,
    unsigned short* __restrict__ ph, unsigned short* __restrict__ pl,
    float* __restrict__ p2) {
    __shared__ float sred[4];
    int b = blockIdx.x;
    int t = threadIdx.x;
    if (b < 2048) {
        size_t base = (size_t)b * 1024 + t;   // float8 index
#pragma unroll
        for (int k = 0; k < 4; ++k) {
            size_t idx = base + (size_t)k * 256;
            const floatx4* src = (const floatx4*)query + idx * 2;
            floatx4 v0 = __builtin_nontemporal_load(src);
            floatx4 v1 = __builtin_nontemporal_load(src + 1);
            ushort8v h, l;
            h[0] = f2bf(v0.x); l[0] = f2bf(v0.x - bf2f(h[0]));
            h[1] = f2bf(v0.y); l[1] = f2bf(v0.y - bf2f(h[1]));
            h[2] = f2bf(v0.z); l[2] = f2bf(v0.z - bf2f(h[2]));
            h[3] = f2bf(v0.w); l[3] = f2bf(v0.w - bf2f(h[3]));
            h[4] = f2bf(v1.x); l[4] = f2bf(v1.x - bf2f(h[4]));
            h[5] = f2bf(v1.y); l[5] = f2bf(v1.y - bf2f(h[5]));
            h[6] = f2bf(v1.z); l[6] = f2bf(v1.z - bf2f(h[6]));
            h[7] = f2bf(v1.w); l[7] = f2bf(v1.w - bf2f(h[7]));
            ((ushort8v*)qh)[idx] = h;   // re-read by GEMM: keep cacheable
            ((ushort8v*)ql)[idx] = l;
        }
    } else {
        // proto part: one block per proto row, also reduce ||p||^2
        int m = b - 2048;
        size_t base4 = (size_t)m * (D_K / 4) + t;
        float4 v = ((const float4*)proto)[base4];
        ushort4 h, l;
        h.x = f2bf(v.x); l.x = f2bf(v.x - bf2f(h.x));
        h.y = f2bf(v.y); l.y = f2bf(v.y - bf2f(h.y));
        h.z = f2bf(v.z); l.z = f2bf(v.z - bf2f(h.z));
        h.w = f2bf(v.w); l.w = f2bf(v.w - bf2f(h.w));
        ((ushort4*)ph)[base4] = h;
        ((ushort4*)pl)[base4] = l;
        float sq = v.x * v.x + v.y * v.y + v.z * v.z + v.w * v.w;
#pragma unroll
        for (int off = 1; off < 64; off <<= 1) sq += __shfl_xor(sq, off);
        if ((t & 63) == 0) sred[t >> 6] = sq;
        __syncthreads();
        if (t == 0) p2[m] = sred[0] + sred[1] + sred[2] + sred[3];
    }
}

// ---------------------------------------------------------------------------
// GEMM: logits[n,m] = 2 * sum_d q[n,d]*p[m,d] - p2[m], via bf16 hi/lo split:
//   qp = qh.ph + qh.pl + ql.ph   (ql.pl dropped, ~1e-4 error)
// 128x128 tile, BK=32, 4 waves -> 2x2 of 64x64, mfma_f32_16x16x32_bf16.
//
// Staging: global side quad-coalesced (lane quad = one row's contiguous
// 64B; scattering lanes across rows cost 4x VMEM transactions in R3).
// LDS bank conflicts broken with an XOR swizzle inside each row's 64B:
// staging lane s fetches (row = s>>2, chunk = (s&3) ^ ((s>>3)&3)); compute
// lane l reads granule 4*(l&15) + ((l>>4) ^ (((l&15)>>1)&3)).
// Measured R4: SQ_LDS_BANK_CONFLICT = 0, 104 us, MfmaUtil 42%.
// ---------------------------------------------------------------------------
__global__ __launch_bounds__(256, 3) void gemm_logits_kernel(
    const unsigned short* __restrict__ qh, const unsigned short* __restrict__ ql,
    const unsigned short* __restrict__ ph, const unsigned short* __restrict__ pl,
    const float* __restrict__ p2, float* __restrict__ out) {
    __shared__ unsigned short lds[4 * 128 * 32];  // Ah | Al | Bh | Bl, 32 KB

    const int tid = threadIdx.x;
    const int wave = tid >> 6;
    const int lane = tid & 63;
    const int nt = blockIdx.x & 127;   // query tile (consecutive blocks share mt)
    const int mt = blockIdx.x >> 7;    // proto tile
    const int row0 = nt * 128;
    const int col0 = mt * 128;

    unsigned short* sAh = lds;
    unsigned short* sAl = lds + 4096;
    unsigned short* sBh = lds + 8192;
    unsigned short* sBl = lds + 12288;

    // Staging assignment: one wave per tile.
    const unsigned short* gsrc;
    unsigned short* ldst;
    int grow0;
    if (wave == 0)      { gsrc = qh; grow0 = row0; ldst = sAh; }
    else if (wave == 1) { gsrc = ql; grow0 = row0; ldst = sAl; }
    else if (wave == 2) { gsrc = ph; grow0 = col0; ldst = sBh; }
    else                { gsrc = pl; grow0 = col0; ldst = sBl; }

    // Quad-coalesced + XOR-swizzled staging source.
    const int rl = lane >> 2;
    const int cio = (lane & 3) ^ ((lane >> 3) & 3);
    const unsigned short* gbase = gsrc + (size_t)(grow0 + rl) * D_K + cio * 8;

    floatx4 zero = {0.0f, 0.0f, 0.0f, 0.0f};
    floatx4 acc[4][4];
#pragma unroll
    for (int i = 0; i < 4; ++i)
#pragma unroll
        for (int j = 0; j < 4; ++j) acc[i][j] = zero;

    const int wrow = (wave & 1) * 64;
    const int wcol = (wave >> 1) * 64;
    const int rsel = lane & 15;
    const int kq = lane >> 4;
    const int sA0 = (wrow >> 4);  // first A subtile index for this wave
    const int sB0 = (wcol >> 4);
    // Swizzled granule for this lane's fragment (within a 64-granule subtile)
    const int gsw = 4 * rsel + (kq ^ ((rsel >> 1) & 3));
    const int fragoff = gsw * 8;  // shorts

    for (int kt = 0; kt < D_K / 32; ++kt) {
        // ---- stage global -> LDS (async, 16B/lane) ----
#pragma unroll
        for (int i = 0; i < 8; ++i) {
            const unsigned short* gp = gbase + (size_t)i * 16 * D_K + kt * 32;
            __builtin_amdgcn_global_load_lds(
                (const AS1 unsigned int*)(const void*)gp,
                (AS3 unsigned int*)(void*)(ldst + i * 512), 16, 0, 0);
        }
        __syncthreads();

        // ---- fragment loads (swizzle-matched, conflict-free) ----
        bf16x8 ah[4], al[4], bh[4], bl[4];
#pragma unroll
        for (int i = 0; i < 4; ++i) {
            const int aoff = (sA0 + i) * 512 + fragoff;
            ah[i] = *(const bf16x8*)(sAh + aoff);
            al[i] = *(const bf16x8*)(sAl + aoff);
            const int boff = (sB0 + i) * 512 + fragoff;
            bh[i] = *(const bf16x8*)(sBh + boff);
            bl[i] = *(const bf16x8*)(sBl + boff);
        }

        // ---- 3-term MFMA accumulate ----
#pragma unroll
        for (int i = 0; i < 4; ++i)
#pragma unroll
            for (int j = 0; j < 4; ++j) {
                acc[i][j] = __builtin_amdgcn_mfma_f32_16x16x32_bf16(ah[i], bh[j], acc[i][j], 0, 0, 0);
                acc[i][j] = __builtin_amdgcn_mfma_f32_16x16x32_bf16(ah[i], bl[j], acc[i][j], 0, 0, 0);
                acc[i][j] = __builtin_amdgcn_mfma_f32_16x16x32_bf16(al[i], bh[j], acc[i][j], 0, 0, 0);
            }
        __syncthreads();
    }

    // ---- epilogue: logits = 2*qp - p2[col] ----
    // C layout (verified m89/m91): col = lane&15, row = (lane>>4)*4 + reg
#pragma unroll
    for (int j = 0; j < 4; ++j) {
        const int gc = col0 + wcol + j * 16 + rsel;
        const float p2v = p2[gc];
#pragma unroll
        for (int i = 0; i < 4; ++i) {
            const int gr = row0 + wrow + i * 16 + kq * 4;
#pragma unroll
            for (int r = 0; r < 4; ++r) {
                out[(size_t)(gr + r) * M_P + gc] = 2.0f * acc[i][j][r] - p2v;
            }
        }
    }
}

// ---------------------------------------------------------------------------
// Fallback (tiny workspace): naive fp32 logits, p2 folded in per-thread.
// ---------------------------------------------------------------------------
__global__ __launch_bounds__(256) void naive_logits_kernel(
    const float* __restrict__ query, const float* __restrict__ proto,
    float* __restrict__ out) {
    __shared__ float qs[D_K];
    int n = blockIdx.x;
    int t = threadIdx.x;
    ((float4*)qs)[t] = ((const float4*)(query + (size_t)n * D_K))[t];
    __syncthreads();
    float acc[4] = {0.f, 0.f, 0.f, 0.f};
    float pp[4] = {0.f, 0.f, 0.f, 0.f};
    for (int d = 0; d < D_K; d += 4) {
        float4 qv = *(const float4*)(qs + d);
#pragma unroll
        for (int j = 0; j < 4; ++j) {
            const float4 pv = *(const float4*)(proto + (size_t)(t + 256 * j) * D_K + d);
            acc[j] += qv.x * pv.x + qv.y * pv.y + qv.z * pv.z + qv.w * pv.w;
            pp[j] += pv.x * pv.x + pv.y * pv.y + pv.z * pv.z + pv.w * pv.w;
        }
    }
#pragma unroll
    for (int j = 0; j < 4; ++j)
        out[(size_t)n * M_P + t + 256 * j] = 2.0f * acc[j] - pp[j];
}

// ---------------------------------------------------------------------------
// In-place row softmax, WAVE-per-row (no LDS, no barriers). Lane l holds
// floats [k*256 + l*4, +4) for k=0..3; 6-step shuffle reductions. Grid-
// stride: 2048 blocks x 4 waves x 2 rows.
// ---------------------------------------------------------------------------
__global__ __launch_bounds__(256) void softmax_kernel(float* __restrict__ out) {
    const int lane = threadIdx.x & 63;
    int n = blockIdx.x * 4 + (threadIdx.x >> 6);
    for (int it = 0; it < 2; ++it, n += 8192) {
        float* row = out + (size_t)n * M_P;
        floatx4 v[4];
#pragma unroll
        for (int k = 0; k < 4; ++k)
            v[k] = *((const floatx4*)(row + k * 256) + lane);
        float mx = fmaxf(fmaxf(v[0].x, v[0].y), fmaxf(v[0].z, v[0].w));
#pragma unroll
        for (int k = 1; k < 4; ++k)
            mx = fmaxf(mx, fmaxf(fmaxf(v[k].x, v[k].y), fmaxf(v[k].z, v[k].w)));
#pragma unroll
        for (int off = 1; off < 64; off <<= 1) mx = fmaxf(mx, __shfl_xor(mx, off));
        float s = 0.0f;
#pragma unroll
        for (int k = 0; k < 4; ++k) {
            v[k].x = __expf(v[k].x - mx);
            v[k].y = __expf(v[k].y - mx);
            v[k].z = __expf(v[k].z - mx);
            v[k].w = __expf(v[k].w - mx);
            s += v[k].x + v[k].y + v[k].z + v[k].w;
        }
#pragma unroll
        for (int off = 1; off < 64; off <<= 1) s += __shfl_xor(s, off);
        const float inv = 1.0f / s;
#pragma unroll
        for (int k = 0; k < 4; ++k) {
            floatx4 o;
            o.x = v[k].x * inv; o.y = v[k].y * inv;
            o.z = v[k].z * inv; o.w = v[k].w * inv;
            __builtin_nontemporal_store(o, (floatx4*)(row + k * 256) + lane);
        }
    }
}

extern "C" void kernel_launch(void* const* d_in, const int* in_sizes, int n_in,
                              void* d_out, int out_size, void* d_ws, size_t ws_size,
                              hipStream_t stream) {
    const float* query = (const float*)d_in[0];
    const float* proto = (const float*)d_in[1];
    float* out = (float*)d_out;

    const size_t qElems = (size_t)N_Q * D_K;   // 16M
    const size_t pElems = (size_t)M_P * D_K;   // 1M
    const size_t needed = qElems * 2 * 2 + pElems * 2 * 2 + M_P * 4;  // ~68 MiB

    if (ws_size >= needed) {
        unsigned short* qh = (unsigned short*)d_ws;
        unsigned short* ql = qh + qElems;
        unsigned short* ph = ql + qElems;
        unsigned short* pl = ph + pElems;
        float* p2 = (float*)(pl + pElems);

        convert_all_kernel<<<2048 + M_P, 256, 0, stream>>>(
            query, qh, ql, proto, ph, pl, p2);
        gemm_logits_kernel<<<(N_Q / 128) * (M_P / 128), 256, 0, stream>>>(
            qh, ql, ph, pl, p2, out);
    } else {
        naive_logits_kernel<<<N_Q, 256, 0, stream>>>(query, proto, out);
    }
    softmax_kernel<<<2048, 256, 0, stream>>>(out);
}